// Round 1
// baseline (361.918 us; speedup 1.0000x reference)
//
#include <hip/hip_runtime.h>
#include <hip/hip_bf16.h>

#define BB 4
#define CC 512
#define NN 4096
#define DD 64   // C8

typedef __attribute__((ext_vector_type(8))) short short8;
typedef __attribute__((ext_vector_type(4))) short short4v;
typedef __attribute__((ext_vector_type(4))) float floatx4;

static __device__ __forceinline__ short f2bf(float f) {
  __hip_bfloat16 h = __float2bfloat16(f);
  return *reinterpret_cast<short*>(&h);
}

static __device__ __forceinline__ floatx4 mfma16(short8 a, short8 b, floatx4 c) {
  return __builtin_amdgcn_mfma_f32_16x16x32_bf16(a, b, c, 0, 0, 0);
}

// ---------------------------------------------------------------------------
// Kernel 0: convert W (Wq rows 0-63, Wk 64-127, Wv 128-639) to bf16, row-major [640][512]
// ---------------------------------------------------------------------------
__global__ void wconv_kernel(const float* __restrict__ Wq, const float* __restrict__ Wk,
                             const float* __restrict__ Wv, short* __restrict__ Wb) {
  int i = blockIdx.x * 256 + threadIdx.x;   // 640*512 = 327680 total
  int row = i >> 9, c = i & 511;
  float v;
  if (row < 64)        v = Wq[(row << 9) | c];
  else if (row < 128)  v = Wk[((row - 64) << 9) | c];
  else                 v = Wv[((row - 128) << 9) | c];
  Wb[i] = f2bf(v);
}

// ---------------------------------------------------------------------------
// Kernel 1: QKV.  Y[n, dout] = sum_c x[b,c,n] * W[dout,c] + bias
//   qb[b][n][d] (dout 0-63), kb[b][n][d] (64-127), vb[b][c][n] (128-639)
// grid: B * N/64 blocks of 512 threads (8 waves); wave w owns dout chunk [80w, 80w+80)
// ---------------------------------------------------------------------------
__global__ __launch_bounds__(512) void qkv_kernel(
    const float* __restrict__ x, const short* __restrict__ Wb,
    const float* __restrict__ bq, const float* __restrict__ bk,
    const float* __restrict__ bv,
    short* __restrict__ qb, short* __restrict__ kb, short* __restrict__ vb) {
  const int b  = blockIdx.x >> 6;
  const int n0 = (blockIdx.x & 63) << 6;
  const int tid = threadIdx.x;
  const int w = tid >> 6, lane = tid & 63;
  const int arow = lane & 15, grp = lane >> 4;

  __shared__ short xs[64][72];   // [n_local][c_local], +8 pad

  floatx4 acc[4][5];
  #pragma unroll
  for (int i = 0; i < 4; ++i)
    #pragma unroll
    for (int j = 0; j < 5; ++j) acc[i][j] = (floatx4){0.f, 0.f, 0.f, 0.f};

  const float* xb = x + (size_t)b * CC * NN;
  const int cidx = tid >> 4;        // 0..31
  const int n4   = (tid & 15) << 2; // 0..60

  for (int c0 = 0; c0 < CC; c0 += 64) {
    __syncthreads();
    // stage x[c0..c0+63][n0..n0+63] -> xs[n][c] (bf16, transposed)
    #pragma unroll
    for (int hh = 0; hh < 2; ++hh) {
      int cl = cidx + hh * 32;
      floatx4 v4 = *(const floatx4*)(xb + (size_t)(c0 + cl) * NN + n0 + n4);
      #pragma unroll
      for (int i = 0; i < 4; ++i) xs[n4 + i][cl] = f2bf(v4[i]);
    }
    __syncthreads();
    #pragma unroll
    for (int ks = 0; ks < 2; ++ks) {
      short8 afr[4];
      #pragma unroll
      for (int ns = 0; ns < 4; ++ns)
        afr[ns] = *(const short8*)&xs[ns * 16 + arow][ks * 32 + grp * 8];
      #pragma unroll
      for (int ds = 0; ds < 5; ++ds) {
        const short* wp = Wb + (size_t)(w * 80 + ds * 16 + arow) * CC + c0 + ks * 32 + grp * 8;
        short8 bfr = *(const short8*)wp;
        #pragma unroll
        for (int ns = 0; ns < 4; ++ns)
          acc[ns][ds] = mfma16(afr[ns], bfr, acc[ns][ds]);
      }
    }
  }

  // epilogue: C rows = n (grp*4+r), cols = dout (arow)
  #pragma unroll
  for (int ds = 0; ds < 5; ++ds) {
    int dout = w * 80 + ds * 16 + arow;
    float bias = (dout < 64) ? bq[dout] : (dout < 128) ? bk[dout - 64] : bv[dout - 128];
    #pragma unroll
    for (int ns = 0; ns < 4; ++ns) {
      int nrow = n0 + ns * 16 + grp * 4;
      floatx4 a = acc[ns][ds];
      if (dout < 64) {
        #pragma unroll
        for (int r = 0; r < 4; ++r)
          qb[((size_t)b * NN + nrow + r) * DD + dout] = f2bf(a[r] + bias);
      } else if (dout < 128) {
        #pragma unroll
        for (int r = 0; r < 4; ++r)
          kb[((size_t)b * NN + nrow + r) * DD + (dout - 64)] = f2bf(a[r] + bias);
      } else {
        short4v pk;
        #pragma unroll
        for (int r = 0; r < 4; ++r) pk[r] = f2bf(a[r] + bias);
        *(short4v*)(vb + ((size_t)b * CC + (dout - 128)) * NN + nrow) = pk;
      }
    }
  }
}

// ---------------------------------------------------------------------------
// Kernel 2: column-softmax stats over the query axis n.
//   s[n,m] = q[n]·k[m]; smax[b,m] = max_n s, ssum[b,m] = sum_n exp(s - smax)
// grid: B * N/32 blocks of 256 threads (4 waves).
// wave w: m16 = w&1 (which 16-m strip), nh = w>>1 (which half of n range)
// ---------------------------------------------------------------------------
__global__ __launch_bounds__(256) void stats_kernel(
    const short* __restrict__ qb, const short* __restrict__ kb,
    float* __restrict__ smax, float* __restrict__ ssum) {
  const int b  = blockIdx.x >> 7;
  const int m0 = (blockIdx.x & 127) << 5;
  const int tid = threadIdx.x;
  const int w = tid >> 6, lane = tid & 63;
  const int arow = lane & 15, grp = lane >> 4;
  const int m16 = w & 1, nh = w >> 1;

  const short* qB = qb + (size_t)b * NN * DD;
  const short* kB = kb + (size_t)b * NN * DD;

  const short* kr = kB + (size_t)(m0 + m16 * 16 + arow) * DD;
  short8 a0 = *(const short8*)(kr + grp * 8);
  short8 a1 = *(const short8*)(kr + 32 + grp * 8);

  float mx[4] = {-1e30f, -1e30f, -1e30f, -1e30f};
  float ls[4] = {0.f, 0.f, 0.f, 0.f};

  for (int nt = 0; nt < NN / 2; nt += 16) {
    const short* qr = qB + (size_t)(nh * (NN / 2) + nt + arow) * DD + grp * 8;
    short8 b0 = *(const short8*)(qr);
    short8 b1 = *(const short8*)(qr + 32);
    floatx4 s4 = (floatx4){0.f, 0.f, 0.f, 0.f};
    s4 = mfma16(a0, b0, s4);
    s4 = mfma16(a1, b1, s4);
    #pragma unroll
    for (int r = 0; r < 4; ++r) {
      float s = s4[r];
      float nm = fmaxf(mx[r], s);
      ls[r] = ls[r] * __expf(mx[r] - nm) + __expf(s - nm);
      mx[r] = nm;
    }
  }
  // merge across the 16 n-residue lanes (cols); stays within lane-group
  #pragma unroll
  for (int off = 1; off < 16; off <<= 1) {
    #pragma unroll
    for (int r = 0; r < 4; ++r) {
      float omx = __shfl_xor(mx[r], off);
      float ols = __shfl_xor(ls[r], off);
      float nm = fmaxf(mx[r], omx);
      ls[r] = ls[r] * __expf(mx[r] - nm) + ols * __expf(omx - nm);
      mx[r] = nm;
    }
  }
  __shared__ float bm[2][2][16], bl[2][2][16];
  if (arow == 0) {
    #pragma unroll
    for (int r = 0; r < 4; ++r) {
      bm[m16][nh][grp * 4 + r] = mx[r];
      bl[m16][nh][grp * 4 + r] = ls[r];
    }
  }
  __syncthreads();
  if (tid < 32) {
    int mi = tid & 15, g16 = tid >> 4;
    float m0v = bm[g16][0][mi], m1v = bm[g16][1][mi];
    float M = fmaxf(m0v, m1v);
    float L = bl[g16][0][mi] * __expf(m0v - M) + bl[g16][1][mi] * __expf(m1v - M);
    smax[(size_t)b * NN + m0 + g16 * 16 + mi] = M;
    ssum[(size_t)b * NN + m0 + g16 * 16 + mi] = L;
  }
}

// ---------------------------------------------------------------------------
// Kernel 3: fused attention. Per block: batch b, m-tile of 64, loop n in 64-blocks.
//   phase1: S[64][64] tiles (8 waves x 2 subtiles), P = exp(S - mx) -> LDS (bf16)
//   phase2: acc[m][c] += P @ vT, wave w owns c-chunk [64w, 64w+64)
//   epilogue: out[b][c][m] = gamma * acc/l + x
// ---------------------------------------------------------------------------
__global__ __launch_bounds__(512) void attn_kernel(
    const short* __restrict__ qb, const short* __restrict__ kb,
    const short* __restrict__ vb, const float* __restrict__ smax,
    const float* __restrict__ ssum, const float* __restrict__ x,
    const float* __restrict__ gamma, float* __restrict__ out) {
  const int b  = blockIdx.x >> 6;
  const int m0 = (blockIdx.x & 63) << 6;
  const int tid = threadIdx.x;
  const int w = tid >> 6, lane = tid & 63;
  const int arow = lane & 15, grp = lane >> 4;

  __shared__ short pbuf[64][72];   // P[m][n] bf16, +8 pad
  __shared__ float sm[64], sl[64];

  if (tid < 64) {
    sm[tid] = smax[(size_t)b * NN + m0 + tid];
    sl[tid] = ssum[(size_t)b * NN + m0 + tid];
  }
  __syncthreads();

  const short* qB = qb + (size_t)b * NN * DD;
  const short* kB = kb + (size_t)b * NN * DD;
  const short* vB = vb + (size_t)b * CC * NN;

  // hoisted kt A-fragments: wave w covers msub = (w>>2)+2h, nsub = w&3
  short8 afr[2][2];
  float smr[2][4];
  #pragma unroll
  for (int h = 0; h < 2; ++h) {
    int msub = (w >> 2) + 2 * h;
    const short* kr = kB + (size_t)(m0 + msub * 16 + arow) * DD;
    afr[h][0] = *(const short8*)(kr + grp * 8);
    afr[h][1] = *(const short8*)(kr + 32 + grp * 8);
    #pragma unroll
    for (int r = 0; r < 4; ++r) smr[h][r] = sm[msub * 16 + grp * 4 + r];
  }

  floatx4 acc[4][4];
  #pragma unroll
  for (int i = 0; i < 4; ++i)
    #pragma unroll
    for (int j = 0; j < 4; ++j) acc[i][j] = (floatx4){0.f, 0.f, 0.f, 0.f};

  const int c0w = w * 64;

  for (int nb = 0; nb < NN; nb += 64) {
    // ---- phase 1: scores + P for this n-block ----
    {
      const short* qr = qB + (size_t)(nb + (w & 3) * 16 + arow) * DD + grp * 8;
      short8 b0 = *(const short8*)(qr);
      short8 b1 = *(const short8*)(qr + 32);
      #pragma unroll
      for (int h = 0; h < 2; ++h) {
        int msub = (w >> 2) + 2 * h;
        floatx4 s4 = (floatx4){0.f, 0.f, 0.f, 0.f};
        s4 = mfma16(afr[h][0], b0, s4);
        s4 = mfma16(afr[h][1], b1, s4);
        int mloc = msub * 16 + grp * 4;
        #pragma unroll
        for (int r = 0; r < 4; ++r) {
          float p = __expf(s4[r] - smr[h][r]);
          pbuf[mloc + r][(w & 3) * 16 + arow] = f2bf(p);
        }
      }
    }
    __syncthreads();
    // ---- phase 2: PV ----
    #pragma unroll
    for (int ks = 0; ks < 2; ++ks) {
      short8 pa[4];
      #pragma unroll
      for (int ms = 0; ms < 4; ++ms)
        pa[ms] = *(const short8*)&pbuf[ms * 16 + arow][ks * 32 + grp * 8];
      #pragma unroll
      for (int cs = 0; cs < 4; ++cs) {
        const short* vp = vB + (size_t)(c0w + cs * 16 + arow) * NN + nb + ks * 32 + grp * 8;
        short8 bv8 = *(const short8*)vp;
        #pragma unroll
        for (int ms = 0; ms < 4; ++ms)
          acc[ms][cs] = mfma16(pa[ms], bv8, acc[ms][cs]);
      }
    }
    __syncthreads();
  }

  const float g = *gamma;
  #pragma unroll
  for (int ms = 0; ms < 4; ++ms) {
    int mloc = ms * 16 + grp * 4;
    int mrow = m0 + mloc;
    floatx4 linv;
    #pragma unroll
    for (int r = 0; r < 4; ++r) linv[r] = g / sl[mloc + r];
    #pragma unroll
    for (int cs = 0; cs < 4; ++cs) {
      int c = c0w + cs * 16 + arow;
      const float* xp = x + ((size_t)b * CC + c) * NN + mrow;
      floatx4 xv = *(const floatx4*)xp;
      floatx4 res;
      #pragma unroll
      for (int r = 0; r < 4; ++r) res[r] = acc[ms][cs][r] * linv[r] + xv[r];
      *(floatx4*)(out + ((size_t)b * CC + c) * NN + mrow) = res;
    }
  }
}

// ---------------------------------------------------------------------------
extern "C" void kernel_launch(void* const* d_in, const int* in_sizes, int n_in,
                              void* d_out, int out_size, void* d_ws, size_t ws_size,
                              hipStream_t stream) {
  const float* x     = (const float*)d_in[0];
  const float* Wq    = (const float*)d_in[1];
  const float* bq    = (const float*)d_in[2];
  const float* Wk    = (const float*)d_in[3];
  const float* bk    = (const float*)d_in[4];
  const float* Wv    = (const float*)d_in[5];
  const float* bv    = (const float*)d_in[6];
  const float* gamma = (const float*)d_in[7];
  float* out = (float*)d_out;

  char* ws = (char*)d_ws;
  short* qb   = (short*)(ws);                               // 2 MB
  short* kb   = (short*)(ws + (2u << 20));                  // 2 MB
  short* vb   = (short*)(ws + (4u << 20));                  // 16 MB
  float* smax = (float*)(ws + (20u << 20));                 // 64 KB
  float* ssum = (float*)(ws + (20u << 20) + (64u << 10));   // 64 KB
  short* Wb   = (short*)(ws + (21u << 20));                 // 640 KB

  hipLaunchKernelGGL(wconv_kernel, dim3(1280), dim3(256), 0, stream, Wq, Wk, Wv, Wb);
  hipLaunchKernelGGL(qkv_kernel, dim3(BB * 64), dim3(512), 0, stream,
                     x, Wb, bq, bk, bv, qb, kb, vb);
  hipLaunchKernelGGL(stats_kernel, dim3(BB * 128), dim3(256), 0, stream,
                     qb, kb, smax, ssum);
  hipLaunchKernelGGL(attn_kernel, dim3(BB * 64), dim3(512), 0, stream,
                     qb, kb, vb, smax, ssum, x, gamma, out);
}

// Round 2
// 314.855 us; speedup vs baseline: 1.1495x; 1.1495x over previous
//
#include <hip/hip_runtime.h>
#include <hip/hip_bf16.h>

#define BB 4
#define CC 512
#define NN 4096
#define DD 64   // C8

typedef __attribute__((ext_vector_type(8))) short short8;
typedef __attribute__((ext_vector_type(4))) short short4v;
typedef __attribute__((ext_vector_type(4))) float floatx4;

static __device__ __forceinline__ short f2bf(float f) {
  __hip_bfloat16 h = __float2bfloat16(f);
  return *reinterpret_cast<short*>(&h);
}

static __device__ __forceinline__ floatx4 mfma16(short8 a, short8 b, floatx4 c) {
  return __builtin_amdgcn_mfma_f32_16x16x32_bf16(a, b, c, 0, 0, 0);
}

// ---------------------------------------------------------------------------
// Kernel 0: convert W (Wq rows 0-63, Wk 64-127, Wv 128-639) to bf16 [640][512]
// ---------------------------------------------------------------------------
__global__ void wconv_kernel(const float* __restrict__ Wq, const float* __restrict__ Wk,
                             const float* __restrict__ Wv, short* __restrict__ Wb) {
  int i = blockIdx.x * 256 + threadIdx.x;   // 640*512 = 327680 total
  int row = i >> 9, c = i & 511;
  float v;
  if (row < 64)        v = Wq[(row << 9) | c];
  else if (row < 128)  v = Wk[((row - 64) << 9) | c];
  else                 v = Wv[((row - 128) << 9) | c];
  Wb[i] = f2bf(v);
}

// ---------------------------------------------------------------------------
// Kernel 1: QKV. Y[n,dout] = sum_c x[b,c,n]*W[dout,c] + bias
//   qb[b][n][d], kb[b][n][d], vb[b][c][n]
// grid: B * N/32 = 512 blocks of 512 threads; wave w owns dout [80w, 80w+80)
// ---------------------------------------------------------------------------
__global__ __launch_bounds__(512, 4) void qkv_kernel(
    const float* __restrict__ x, const short* __restrict__ Wb,
    const float* __restrict__ bq, const float* __restrict__ bk,
    const float* __restrict__ bv,
    short* __restrict__ qb, short* __restrict__ kb, short* __restrict__ vb) {
  const int b  = blockIdx.x >> 7;
  const int n0 = (blockIdx.x & 127) << 5;
  const int tid = threadIdx.x;
  const int w = tid >> 6, lane = tid & 63;
  const int arow = lane & 15, grp = lane >> 4;

  __shared__ short xs[32][72];   // [n_local][c_local], +8 pad

  floatx4 acc[2][5];
  #pragma unroll
  for (int i = 0; i < 2; ++i)
    #pragma unroll
    for (int j = 0; j < 5; ++j) acc[i][j] = (floatx4){0.f, 0.f, 0.f, 0.f};

  const float* xb = x + (size_t)b * CC * NN;
  const int cidx = tid >> 3;        // 0..63
  const int n4   = (tid & 7) << 2;  // 0..28

  for (int c0 = 0; c0 < CC; c0 += 64) {
    floatx4 v4 = *(const floatx4*)(xb + (size_t)(c0 + cidx) * NN + n0 + n4);
    __syncthreads();
    #pragma unroll
    for (int i = 0; i < 4; ++i) xs[n4 + i][cidx] = f2bf(v4[i]);
    __syncthreads();
    #pragma unroll
    for (int ks = 0; ks < 2; ++ks) {
      short8 afr[2];
      #pragma unroll
      for (int ns = 0; ns < 2; ++ns)
        afr[ns] = *(const short8*)&xs[ns * 16 + arow][ks * 32 + grp * 8];
      #pragma unroll
      for (int ds = 0; ds < 5; ++ds) {
        const short* wp = Wb + (size_t)(w * 80 + ds * 16 + arow) * CC + c0 + ks * 32 + grp * 8;
        short8 bfr = *(const short8*)wp;
        #pragma unroll
        for (int ns = 0; ns < 2; ++ns)
          acc[ns][ds] = mfma16(afr[ns], bfr, acc[ns][ds]);
      }
    }
  }

  #pragma unroll
  for (int ds = 0; ds < 5; ++ds) {
    int dout = w * 80 + ds * 16 + arow;
    float bias = (dout < 64) ? bq[dout] : (dout < 128) ? bk[dout - 64] : bv[dout - 128];
    #pragma unroll
    for (int ns = 0; ns < 2; ++ns) {
      int nrow = n0 + ns * 16 + grp * 4;
      floatx4 a = acc[ns][ds];
      if (dout < 64) {
        #pragma unroll
        for (int r = 0; r < 4; ++r)
          qb[((size_t)b * NN + nrow + r) * DD + dout] = f2bf(a[r] + bias);
      } else if (dout < 128) {
        #pragma unroll
        for (int r = 0; r < 4; ++r)
          kb[((size_t)b * NN + nrow + r) * DD + (dout - 64)] = f2bf(a[r] + bias);
      } else {
        short4v pk;
        #pragma unroll
        for (int r = 0; r < 4; ++r) pk[r] = f2bf(a[r] + bias);
        *(short4v*)(vb + ((size_t)b * CC + (dout - 128)) * NN + nrow) = pk;
      }
    }
  }
}

// ---------------------------------------------------------------------------
// Kernel 2: fused attention, self-normalizing (no max subtraction; denominator
// accumulated in-register). Block: (b, m-tile 64, c-half 256). 8 waves.
//   phase1: S tiles -> P=exp(S) -> pbuf[buf] (bf16), dl += p
//   phase2: acc[m][c] += P @ vT, wave owns 32 channels
//   epilogue: l[m] = sum of dl partials; out = gamma*acc/l + x
// ---------------------------------------------------------------------------
__global__ __launch_bounds__(512, 4) void attn_kernel(
    const short* __restrict__ qb, const short* __restrict__ kb,
    const short* __restrict__ vb, const float* __restrict__ x,
    const float* __restrict__ gamma, float* __restrict__ out) {
  const int bm = blockIdx.x >> 1;
  const int ch = blockIdx.x & 1;
  const int b  = bm >> 6;
  const int m0 = (bm & 63) << 6;
  const int tid = threadIdx.x;
  const int w = tid >> 6, lane = tid & 63;
  const int arow = lane & 15, grp = lane >> 4;
  const int nsub = w & 3;

  __shared__ short pbuf[2][64][72];   // P[m][n] bf16, double-buffered
  __shared__ float dsum[4][64];

  const short* qB = qb + (size_t)b * NN * DD;
  const short* kB = kb + (size_t)b * NN * DD;
  const short* vB = vb + (size_t)b * CC * NN;

  // hoisted kt A-fragments: wave w covers msub = (w>>2)+2h
  short8 afr[2][2];
  #pragma unroll
  for (int h = 0; h < 2; ++h) {
    int msub = (w >> 2) + 2 * h;
    const short* kr = kB + (size_t)(m0 + msub * 16 + arow) * DD;
    afr[h][0] = *(const short8*)(kr + grp * 8);
    afr[h][1] = *(const short8*)(kr + 32 + grp * 8);
  }

  floatx4 acc[4][2];    // [ms][cs]
  #pragma unroll
  for (int i = 0; i < 4; ++i)
    #pragma unroll
    for (int j = 0; j < 2; ++j) acc[i][j] = (floatx4){0.f, 0.f, 0.f, 0.f};
  float dl[2][4];
  #pragma unroll
  for (int h = 0; h < 2; ++h)
    #pragma unroll
    for (int r = 0; r < 4; ++r) dl[h][r] = 0.f;

  const int c0w = ch * 256 + w * 32;

  // prologue: q fragments for nb=0
  const short* qr0 = qB + (size_t)(nsub * 16 + arow) * DD + grp * 8;
  short8 q0 = *(const short8*)(qr0);
  short8 q1 = *(const short8*)(qr0 + 32);

  int buf = 0;
  for (int nb = 0; nb < NN; nb += 64) {
    // ---- phase 1: P for this n-block ----
    #pragma unroll
    for (int h = 0; h < 2; ++h) {
      int msub = (w >> 2) + 2 * h;
      floatx4 s4 = (floatx4){0.f, 0.f, 0.f, 0.f};
      s4 = mfma16(afr[h][0], q0, s4);
      s4 = mfma16(afr[h][1], q1, s4);
      int mloc = msub * 16 + grp * 4;
      #pragma unroll
      for (int r = 0; r < 4; ++r) {
        float p = __expf(s4[r]);
        dl[h][r] += p;
        pbuf[buf][mloc + r][nsub * 16 + arow] = f2bf(p);
      }
    }
    // prefetch q for next n-block (wraps harmlessly at the end)
    {
      int nbn = (nb + 64) & (NN - 1);
      const short* qr = qB + (size_t)(nbn + nsub * 16 + arow) * DD + grp * 8;
      q0 = *(const short8*)(qr);
      q1 = *(const short8*)(qr + 32);
    }
    // prefetch v (ks=0) before the barrier
    short8 vr0[2];
    #pragma unroll
    for (int cs = 0; cs < 2; ++cs)
      vr0[cs] = *(const short8*)(vB + (size_t)(c0w + cs * 16 + arow) * NN + nb + grp * 8);
    __syncthreads();
    // ---- phase 2: PV ----
    short8 pa[4];
    #pragma unroll
    for (int ms = 0; ms < 4; ++ms)
      pa[ms] = *(const short8*)&pbuf[buf][ms * 16 + arow][grp * 8];
    short8 vr1[2];
    #pragma unroll
    for (int cs = 0; cs < 2; ++cs)
      vr1[cs] = *(const short8*)(vB + (size_t)(c0w + cs * 16 + arow) * NN + nb + 32 + grp * 8);
    #pragma unroll
    for (int cs = 0; cs < 2; ++cs)
      #pragma unroll
      for (int ms = 0; ms < 4; ++ms)
        acc[ms][cs] = mfma16(pa[ms], vr0[cs], acc[ms][cs]);
    #pragma unroll
    for (int ms = 0; ms < 4; ++ms)
      pa[ms] = *(const short8*)&pbuf[buf][ms * 16 + arow][32 + grp * 8];
    #pragma unroll
    for (int cs = 0; cs < 2; ++cs)
      #pragma unroll
      for (int ms = 0; ms < 4; ++ms)
        acc[ms][cs] = mfma16(pa[ms], vr1[cs], acc[ms][cs]);
    buf ^= 1;
  }

  // denominator: reduce dl across the 16 n-lanes, combine nsub partials in LDS
  #pragma unroll
  for (int off = 1; off < 16; off <<= 1)
    #pragma unroll
    for (int h = 0; h < 2; ++h)
      #pragma unroll
      for (int r = 0; r < 4; ++r)
        dl[h][r] += __shfl_xor(dl[h][r], off);
  if (arow == 0) {
    #pragma unroll
    for (int h = 0; h < 2; ++h) {
      int msub = (w >> 2) + 2 * h;
      #pragma unroll
      for (int r = 0; r < 4; ++r)
        dsum[nsub][msub * 16 + grp * 4 + r] = dl[h][r];
    }
  }
  __syncthreads();

  const float g = *gamma;
  #pragma unroll
  for (int ms = 0; ms < 4; ++ms) {
    int mloc = ms * 16 + grp * 4;
    int mrow = m0 + mloc;
    floatx4 linv;
    #pragma unroll
    for (int r = 0; r < 4; ++r) {
      float l = dsum[0][mloc + r] + dsum[1][mloc + r] + dsum[2][mloc + r] + dsum[3][mloc + r];
      linv[r] = g / l;
    }
    #pragma unroll
    for (int cs = 0; cs < 2; ++cs) {
      int c = c0w + cs * 16 + arow;
      const float* xp = x + ((size_t)b * CC + c) * NN + mrow;
      floatx4 xv = *(const floatx4*)xp;
      floatx4 res;
      #pragma unroll
      for (int r = 0; r < 4; ++r) res[r] = acc[ms][cs][r] * linv[r] + xv[r];
      *(floatx4*)(out + ((size_t)b * CC + c) * NN + mrow) = res;
    }
  }
}

// ---------------------------------------------------------------------------
extern "C" void kernel_launch(void* const* d_in, const int* in_sizes, int n_in,
                              void* d_out, int out_size, void* d_ws, size_t ws_size,
                              hipStream_t stream) {
  const float* x     = (const float*)d_in[0];
  const float* Wq    = (const float*)d_in[1];
  const float* bq    = (const float*)d_in[2];
  const float* Wk    = (const float*)d_in[3];
  const float* bk    = (const float*)d_in[4];
  const float* Wv    = (const float*)d_in[5];
  const float* bv    = (const float*)d_in[6];
  const float* gamma = (const float*)d_in[7];
  float* out = (float*)d_out;

  char* ws = (char*)d_ws;
  short* qb = (short*)(ws);                // 2 MB
  short* kb = (short*)(ws + (2u << 20));   // 2 MB
  short* vb = (short*)(ws + (4u << 20));   // 16 MB
  short* Wb = (short*)(ws + (21u << 20));  // 640 KB

  hipLaunchKernelGGL(wconv_kernel, dim3(1280), dim3(256), 0, stream, Wq, Wk, Wv, Wb);
  hipLaunchKernelGGL(qkv_kernel, dim3(BB * 128), dim3(512), 0, stream,
                     x, Wb, bq, bk, bv, qb, kb, vb);
  hipLaunchKernelGGL(attn_kernel, dim3(BB * 64 * 2), dim3(512), 0, stream,
                     qb, kb, vb, x, gamma, out);
}